// Round 1
// baseline (135.730 us; speedup 1.0000x reference)
//
#include <hip/hip_runtime.h>

#define SS 512
#define NVERT (SS * SS)
#define NBATCH 16
#define EPSF 1e-12f

struct V3 { float x, y, z; };

__device__ __forceinline__ V3 loadv(const float* __restrict__ p, int idx) {
    const float* q = p + 3 * (size_t)idx;
    V3 r; r.x = q[0]; r.y = q[1]; r.z = q[2]; return r;
}

__device__ __forceinline__ V3 subv(V3 a, V3 b) { return {a.x - b.x, a.y - b.y, a.z - b.z}; }

__device__ __forceinline__ V3 crossv(V3 a, V3 b) {
    return {a.y * b.z - a.z * b.y,
            a.z * b.x - a.x * b.z,
            a.x * b.y - a.y * b.x};
}

__global__ __launch_bounds__(256) void VertexNormals_kernel(
        const float* __restrict__ vrt, float* __restrict__ out) {
    int tid = blockIdx.x * blockDim.x + threadIdx.x;   // exactly NBATCH*NVERT threads
    int b = tid >> 18;            // NVERT = 2^18
    int v = tid & (NVERT - 1);
    int r = v >> 9;               // SS = 2^9
    int c = v & (SS - 1);

    const float* base = vrt + (size_t)b * (3 * NVERT);

    int rm1 = (r > 0)      ? r - 1 : 0;
    int rp1 = (r < SS - 1) ? r + 1 : SS - 1;
    int cm1 = (c > 0)      ? c - 1 : 0;
    int cp1 = (c < SS - 1) ? c + 1 : SS - 1;

    // 7-point stencil (clamped loads; validity handled by flags below)
    V3 pcc = loadv(base, r   * SS + c  );
    V3 pmc = loadv(base, rm1 * SS + c  );
    V3 ppc = loadv(base, rp1 * SS + c  );
    V3 pcm = loadv(base, r   * SS + cm1);
    V3 pcp = loadv(base, r   * SS + cp1);
    V3 pmp = loadv(base, rm1 * SS + cp1);
    V3 ppm = loadv(base, rp1 * SS + cm1);

    bool rm = (r > 0), rp = (r < SS - 1), cm = (c > 0), cp = (c < SS - 1);

    float ax = 0.f, ay = 0.f, az = 0.f;
    auto addf = [&](V3 p0, V3 p1, V3 p2) {
        V3 u = subv(p1, p0);
        V3 w = subv(p2, p0);
        V3 n = crossv(u, w);
        float len = sqrtf(n.x * n.x + n.y * n.y + n.z * n.z);
        float inv = 1.0f / fmaxf(len, EPSF);
        ax += n.x * inv; ay += n.y * inv; az += n.z * inv;
    };

    // triangles adjacent to vertex (r,c); winding matches reference faces
    if (rp & cp) addf(pcc, ppc, pcp);                                // t1 @ (r,  c)
    if (rm & cp) { addf(pmc, pcc, pmp); addf(pmp, pcc, pcp); }       // t1,t2 @ (r-1,c)
    if (rp & cm) { addf(pcm, ppm, pcc); addf(pcc, ppm, ppc); }       // t1,t2 @ (r,c-1)
    if (rm & cm) addf(pmc, pcm, pcc);                                // t2 @ (r-1,c-1)

    float len = sqrtf(ax * ax + ay * ay + az * az);
    float inv = 1.0f / fmaxf(len, EPSF);

    float* o = out + 3 * (size_t)tid;
    o[0] = ax * inv; o[1] = ay * inv; o[2] = az * inv;
}

extern "C" void kernel_launch(void* const* d_in, const int* in_sizes, int n_in,
                              void* d_out, int out_size, void* d_ws, size_t ws_size,
                              hipStream_t stream) {
    const float* vrt = (const float*)d_in[0];   // (16, 512*512, 3) fp32
    float* out = (float*)d_out;                 // (16, 512*512, 3) fp32

    const int total = NBATCH * NVERT;           // 4,194,304
    const int block = 256;
    const int grid = total / block;             // 16384

    hipLaunchKernelGGL(VertexNormals_kernel, dim3(grid), dim3(block), 0, stream,
                       vrt, out);
}

// Round 2
// 124.255 us; speedup vs baseline: 1.0923x; 1.0923x over previous
//
#include <hip/hip_runtime.h>

#define SS 512
#define NVERT (SS * SS)
#define NBATCH 16

struct V3 { float x, y, z; };

__device__ __forceinline__ V3 loadv(const float* __restrict__ p, int idx) {
    const float* q = p + 3 * (size_t)idx;
    V3 r; r.x = q[0]; r.y = q[1]; r.z = q[2]; return r;
}

__device__ __forceinline__ V3 subv(V3 a, V3 b) { return {a.x - b.x, a.y - b.y, a.z - b.z}; }

__device__ __forceinline__ V3 crossv(V3 a, V3 b) {
    return {a.y * b.z - a.z * b.y,
            a.z * b.x - a.x * b.z,
            a.x * b.y - a.y * b.x};
}

// 1/max(sqrt(d), 1e-12)  ==  rsqrt(max(d, 1e-24)), single v_rsq_f32 (~1 ulp).
// Avoids the correctly-rounded sqrt+divide sequences (~20 VALU insts each).
__device__ __forceinline__ float rsq_eps(float d) {
    return __builtin_amdgcn_rsqf(fmaxf(d, 1e-24f));
}

__global__ __launch_bounds__(256) void VertexNormals_kernel(
        const float* __restrict__ vrt, float* __restrict__ out) {
    int tid = blockIdx.x * blockDim.x + threadIdx.x;   // exactly NBATCH*NVERT threads
    int b = tid >> 18;            // NVERT = 2^18
    int v = tid & (NVERT - 1);
    int r = v >> 9;               // SS = 2^9
    int c = v & (SS - 1);

    const float* base = vrt + (size_t)b * (3 * NVERT);

    int rm1 = (r > 0)      ? r - 1 : 0;
    int rp1 = (r < SS - 1) ? r + 1 : SS - 1;
    int cm1 = (c > 0)      ? c - 1 : 0;
    int cp1 = (c < SS - 1) ? c + 1 : SS - 1;

    // 7-point stencil (clamped loads; validity handled by flags below)
    V3 pcc = loadv(base, r   * SS + c  );
    V3 pmc = loadv(base, rm1 * SS + c  );
    V3 ppc = loadv(base, rp1 * SS + c  );
    V3 pcm = loadv(base, r   * SS + cm1);
    V3 pcp = loadv(base, r   * SS + cp1);
    V3 pmp = loadv(base, rm1 * SS + cp1);
    V3 ppm = loadv(base, rp1 * SS + cm1);

    bool rm = (r > 0), rp = (r < SS - 1), cm = (c > 0), cp = (c < SS - 1);

    float ax = 0.f, ay = 0.f, az = 0.f;
    auto addf = [&](V3 p0, V3 p1, V3 p2) {
        V3 u = subv(p1, p0);
        V3 w = subv(p2, p0);
        V3 n = crossv(u, w);
        float inv = rsq_eps(n.x * n.x + n.y * n.y + n.z * n.z);
        ax += n.x * inv; ay += n.y * inv; az += n.z * inv;
    };

    // triangles adjacent to vertex (r,c); winding matches reference faces
    if (rp & cp) addf(pcc, ppc, pcp);                                // t1 @ (r,  c)
    if (rm & cp) { addf(pmc, pcc, pmp); addf(pmp, pcc, pcp); }       // t1,t2 @ (r-1,c)
    if (rp & cm) { addf(pcm, ppm, pcc); addf(pcc, ppm, ppc); }       // t1,t2 @ (r,c-1)
    if (rm & cm) addf(pmc, pcm, pcc);                                // t2 @ (r-1,c-1)

    float inv = rsq_eps(ax * ax + ay * ay + az * az);

    float* o = out + 3 * (size_t)tid;
    o[0] = ax * inv; o[1] = ay * inv; o[2] = az * inv;
}

extern "C" void kernel_launch(void* const* d_in, const int* in_sizes, int n_in,
                              void* d_out, int out_size, void* d_ws, size_t ws_size,
                              hipStream_t stream) {
    const float* vrt = (const float*)d_in[0];   // (16, 512*512, 3) fp32
    float* out = (float*)d_out;                 // (16, 512*512, 3) fp32

    const int total = NBATCH * NVERT;           // 4,194,304
    const int block = 256;
    const int grid = total / block;             // 16384

    hipLaunchKernelGGL(VertexNormals_kernel, dim3(grid), dim3(block), 0, stream,
                       vrt, out);
}